// Round 7
// baseline (3067.982 us; speedup 1.0000x reference)
//
#include <hip/hip_runtime.h>
#include <math.h>

#define NPAD 65

// ---------- small device helpers ----------
__device__ __forceinline__ float leaky(float x) { return x > 0.f ? x : 0.01f * x; }
__device__ __forceinline__ float eluf(float x)  { return x > 0.f ? x : (__expf(x) - 1.f); }
__device__ __forceinline__ float sigm(float x)  { return 1.f / (1.f + __expf(-x)); }
__device__ __forceinline__ float tanhfast(float x) { return 1.f - 2.f / (__expf(2.f * x) + 1.f); }

__device__ __forceinline__ float bcastf(float v, int k) {
    return __uint_as_float((unsigned)__builtin_amdgcn_readlane((int)__float_as_uint(v), k));
}
__device__ __forceinline__ int bcasti(int v, int k) {
    return __builtin_amdgcn_readlane(v, k);
}
__device__ __forceinline__ float wredsum(float v) {
    #pragma unroll
    for (int off = 32; off; off >>= 1) v += __shfl_xor(v, off);
    return v;
}
__device__ __forceinline__ float wredmax(float v) {
    #pragma unroll
    for (int off = 32; off; off >>= 1) v = fmaxf(v, __shfl_xor(v, off));
    return v;
}

// ================= CSR build =================
__global__ __launch_bounds__(256) void k_hist(const int* __restrict__ ei, int* __restrict__ deg, int E_) {
    int e = blockIdx.x * 256 + threadIdx.x;
    if (e < E_) atomicAdd(&deg[ei[E_ + e]], 1);
}

__global__ __launch_bounds__(256) void k_scan1(const int* __restrict__ deg, int* __restrict__ bsum, int N_) {
    __shared__ int s[256];
    int i = blockIdx.x * 256 + threadIdx.x;
    s[threadIdx.x] = (i < N_) ? deg[i] : 0;
    __syncthreads();
    for (int off = 128; off; off >>= 1) {
        if (threadIdx.x < off) s[threadIdx.x] += s[threadIdx.x + off];
        __syncthreads();
    }
    if (threadIdx.x == 0) bsum[blockIdx.x] = s[0];
}

// parallel exclusive scan of block sums (single block, chunked w/ carry)
__global__ __launch_bounds__(512) void k_scan2(int* __restrict__ bsum, int nb) {
    __shared__ int s[512];
    __shared__ int carry_s;
    if (threadIdx.x == 0) carry_s = 0;
    __syncthreads();
    for (int base = 0; base < nb; base += 512) {
        int t = threadIdx.x;
        int idx = base + t;
        int v = (idx < nb) ? bsum[idx] : 0;
        s[t] = v;
        __syncthreads();
        #pragma unroll
        for (int off = 1; off < 512; off <<= 1) {
            int u = (t >= off) ? s[t - off] : 0;
            __syncthreads();
            s[t] += u;
            __syncthreads();
        }
        int carry = carry_s;
        if (idx < nb) bsum[idx] = carry + s[t] - v;   // exclusive
        __syncthreads();
        if (t == 0) carry_s = carry + s[511];
        __syncthreads();
    }
}

__global__ __launch_bounds__(256) void k_scan3(const int* __restrict__ deg, const int* __restrict__ bsum,
                                               int* __restrict__ row, int* __restrict__ cur, int N_, int E_) {
    __shared__ int s[256];
    int i = blockIdx.x * 256 + threadIdx.x;
    int d = (i < N_) ? deg[i] : 0;
    s[threadIdx.x] = d;
    __syncthreads();
    for (int off = 1; off < 256; off <<= 1) {
        int v = (threadIdx.x >= off) ? s[threadIdx.x - off] : 0;
        __syncthreads();
        s[threadIdx.x] += v;
        __syncthreads();
    }
    if (i < N_) {
        int ex = bsum[blockIdx.x] + s[threadIdx.x] - d;
        row[i] = ex; cur[i] = ex;
    }
    if (i == N_ - 1) row[N_] = E_;
}

__global__ __launch_bounds__(256) void k_scatter(const int* __restrict__ ei, int* __restrict__ cur,
                                                 int* __restrict__ csrc, int* __restrict__ ceid, int E_) {
    int e = blockIdx.x * 256 + threadIdx.x;
    if (e >= E_) return;
    int dst = ei[E_ + e];
    int slot = atomicAdd(&cur[dst], 1);
    csrc[slot] = ei[e];
    ceid[slot] = e;
}

__global__ __launch_bounds__(256) void k_gbounds(const int* __restrict__ batch, int* __restrict__ gst,
                                                 int N_, int G_) {
    int i = blockIdx.x * 256 + threadIdx.x;
    if (i >= N_) return;
    int b = batch[i];
    int prev = (i == 0) ? -1 : batch[i - 1];
    for (int g = prev + 1; g <= b; ++g) gst[g] = i;
    if (i == N_ - 1) { for (int g = b + 1; g <= G_; ++g) gst[g] = N_; }
}

// ---------- dense64: out = act(in @ w^T + b), w row-stride = wstride ----------
// weights staged per 16-k slice into LDS; reads are wave-uniform broadcasts
__global__ __launch_bounds__(256) void k_dense64(
    const float* __restrict__ in, const float* __restrict__ w, int wstride,
    const float* __restrict__ b, float* __restrict__ outp, int M, int act)
{
    __shared__ float ti[64 * NPAD];
    __shared__ float to[64 * NPAD];
    __shared__ float ws[64 * 16];
    int r0 = blockIdx.x * 64;
    for (int i = threadIdx.x; i < 4096; i += 256) {
        int r = i >> 6, c = i & 63; int gr = r0 + r;
        ti[r * NPAD + c] = (gr < M) ? in[(size_t)gr * 64 + c] : 0.f;
    }
    int n = threadIdx.x & 63;
    int jl = __builtin_amdgcn_readfirstlane((threadIdx.x >> 6) << 4);
    float acc[16];
    #pragma unroll
    for (int jj = 0; jj < 16; ++jj) acc[jj] = b[jl + jj];
    for (int kcc = 0; kcc < 4; ++kcc) {
        int kc = kcc << 4;
        {   // stage 64 rows x 16 cols (256 float4, one per thread)
            int rrow = threadIdx.x >> 2, q = threadIdx.x & 3;
            *(float4*)&ws[rrow * 16 + q * 4] =
                *(const float4*)(w + (size_t)rrow * wstride + kc + q * 4);
        }
        __syncthreads();
        #pragma unroll
        for (int half = 0; half < 2; ++half) {
            int kb = kc + (half << 3), co = half << 3;
            float xr[8];
            #pragma unroll
            for (int i = 0; i < 8; ++i) xr[i] = ti[n * NPAD + kb + i];
            #pragma unroll
            for (int jj = 0; jj < 16; ++jj) {
                const float* wr = ws + (jl + jj) * 16 + co;
                #pragma unroll
                for (int i = 0; i < 8; ++i) acc[jj] = fmaf(wr[i], xr[i], acc[jj]);
            }
        }
        __syncthreads();
    }
    #pragma unroll
    for (int jj = 0; jj < 16; ++jj) {
        float v = acc[jj];
        to[n * NPAD + jl + jj] = act ? leaky(v) : v;
    }
    __syncthreads();
    for (int i = threadIdx.x; i < 4096; i += 256) {
        int r = i >> 6, c = i & 63; int gr = r0 + r;
        if (gr < M) outp[(size_t)gr * 64 + c] = to[r * NPAD + c];
    }
}

// ---------- per-node dot(s) with align vectors ----------
__global__ __launch_bounds__(256) void k_node_dot2(
    const float* __restrict__ x, const float* __restrict__ wa,
    const float* __restrict__ wb, float* __restrict__ s,
    float* __restrict__ t, int n, int two)
{
    int gt = blockIdx.x * 256 + threadIdx.x;
    int wid = gt >> 6, lane = threadIdx.x & 63;
    if (wid >= n) return;
    float xv = x[(size_t)wid * 64 + lane];
    float a = xv * wa[lane];
    float bb = two ? xv * wb[lane] : 0.f;
    #pragma unroll
    for (int off = 32; off; off >>= 1) {
        a  += __shfl_down(a, off);
        bb += __shfl_down(bb, off);
    }
    if (lane == 0) { s[wid] = a; if (two) t[wid] = bb; }
}

// ---------- GATE layer: wave per dst node, online softmax gather ----------
__global__ __launch_bounds__(256) void k_gate_gather(
    const float* __restrict__ u, const float* __restrict__ ea,
    const int* __restrict__ row, const int* __restrict__ csrc, const int* __restrict__ ceid,
    const float* __restrict__ wnl,
    const float* __restrict__ gaw, const float* __restrict__ gab,
    const float* __restrict__ sarr, float* __restrict__ Agg, int N_)
{
    int wid = (blockIdx.x * 256 + threadIdx.x) >> 6;
    int lane = threadIdx.x & 63;
    if (wid >= N_) return;
    float w2[16];
    #pragma unroll
    for (int k = 0; k < 16; ++k) w2[k] = wnl[lane * 80 + 64 + k];
    float g2 = gaw[64 + lane];
    float gb = gab[0];
    float sdst = sarr[wid];
    int beg = row[wid], end = row[wid + 1];
    float m = -INFINITY, d = 0.f, S = 0.f;
    for (int cs = beg; cs < end; cs += 64) {
        int cnt = min(64, end - cs);
        int src_l = 0, eid_l = 0;
        if (lane < cnt) { src_l = csrc[cs + lane]; eid_l = ceid[cs + lane]; }
        for (int l = 0; l < cnt; ++l) {
            int src = bcasti(src_l, l), eid = bcasti(eid_l, l);
            float acc = u[(size_t)src * 64 + lane];
            const float* er = ea + (size_t)eid * 16;
            #pragma unroll
            for (int k = 0; k < 16; ++k) acc = fmaf(er[k], w2[k], acc);
            float xj = leaky(acc);
            float t = wredsum(xj * g2);
            float sc = leaky(sdst + t + gb);
            float mn = fmaxf(m, sc);
            float c = __expf(m - mn), w = __expf(sc - mn);
            S = S * c + w * xj;
            d = d * c + w;
            m = mn;
        }
    }
    Agg[(size_t)wid * 64 + lane] = S / (d + 1e-16f);
}

// ---------- GAT layer: wave per dst node, chunked online softmax gather ----------
__global__ __launch_bounds__(256) void k_gat_gather(
    const int* __restrict__ row, const int* __restrict__ csrc,
    const float* __restrict__ x, const float* __restrict__ sarr,
    const float* __restrict__ tarr, const float* __restrict__ cb,
    float* __restrict__ Agg, int N_)
{
    int wid = (blockIdx.x * 256 + threadIdx.x) >> 6;
    int lane = threadIdx.x & 63;
    if (wid >= N_) return;
    float sdst = sarr[wid];
    float cbv = cb[0];
    int beg = row[wid], end = row[wid + 1];
    float m = -INFINITY, d = 0.f, S = 0.f;
    for (int cs = beg; cs < end; cs += 64) {
        int cnt = min(64, end - cs);
        float sc_l = -INFINITY; int src_l = 0;
        if (lane < cnt) {
            src_l = csrc[cs + lane];
            sc_l = leaky(sdst + tarr[src_l] + cbv);
        }
        float cmax = wredmax(sc_l);
        float mn = fmaxf(m, cmax);
        float c = __expf(m - mn);
        float w_l = __expf(sc_l - mn);
        d = d * c + wredsum(w_l);
        S *= c;
        int l = 0;
        for (; l + 4 <= cnt; l += 4) {
            int s0 = bcasti(src_l, l), s1 = bcasti(src_l, l + 1);
            int s2 = bcasti(src_l, l + 2), s3 = bcasti(src_l, l + 3);
            float w0 = bcastf(w_l, l), w1 = bcastf(w_l, l + 1);
            float w2 = bcastf(w_l, l + 2), w3 = bcastf(w_l, l + 3);
            float r0 = x[(size_t)s0 * 64 + lane];
            float r1 = x[(size_t)s1 * 64 + lane];
            float r2 = x[(size_t)s2 * 64 + lane];
            float r3 = x[(size_t)s3 * 64 + lane];
            S = fmaf(w0, r0, S); S = fmaf(w1, r1, S);
            S = fmaf(w2, r2, S); S = fmaf(w3, r3, S);
        }
        for (; l < cnt; ++l) {
            float wl = bcastf(w_l, l);
            int srcl = bcasti(src_l, l);
            S = fmaf(wl, x[(size_t)srcl * 64 + lane], S);
        }
        m = mn;
    }
    Agg[(size_t)wid * 64 + lane] = S / (d + 1e-16f);
}

// ---------- fused node update, LDS-staged weights (spill-safe) ----------
// h = elu(Agg@Wa^T + ba); out = relu(GRU(h, x)); optionally emits align dots.
// Weights staged per 16-k slice into ws; compute split into 8-wide halves so
// only hr_[8]/xr_[8] are live (R6's hr_[16]/xr_[16] caused scratch spills:
// WRITE_SIZE 25->325 MB). All weight reads are wave-uniform LDS broadcasts.
__global__ __launch_bounds__(512, 4) void k_node_update(
    const float* __restrict__ agg, const float* __restrict__ xold,
    const float* __restrict__ wa, const float* __restrict__ ba,
    const float* __restrict__ wih, const float* __restrict__ whh,
    const float* __restrict__ bih, const float* __restrict__ bhh,
    float* __restrict__ xout, int M,
    const float* __restrict__ dwa, const float* __restrict__ dwb,
    float* __restrict__ sout, float* __restrict__ tout)
{
    __shared__ float tA[64 * NPAD];   // agg tile, then h tile, then out tile
    __shared__ float tX[64 * NPAD];   // xold tile
    __shared__ float ws[384 * 16];    // weight slice buffer (24 KB)
    int r0 = blockIdx.x * 64;
    for (int i = threadIdx.x; i < 4096; i += 512) {
        int r = i >> 6, c = i & 63; int gr = r0 + r;
        float av = 0.f, xv = 0.f;
        if (gr < M) { av = agg[(size_t)gr * 64 + c]; xv = xold[(size_t)gr * 64 + c]; }
        tA[r * NPAD + c] = av; tX[r * NPAD + c] = xv;
    }
    int n = threadIdx.x & 63;
    int jl = __builtin_amdgcn_readfirstlane((threadIdx.x >> 6) << 3);  // 0..56

    // Phase B: h[jl..jl+8) = elu(Agg @ Wa^T + ba)
    float hv[8];
    {
        float acc[8];
        #pragma unroll
        for (int jj = 0; jj < 8; ++jj) acc[jj] = ba[jl + jj];
        for (int kcc = 0; kcc < 4; ++kcc) {
            int kc = kcc << 4;
            if (threadIdx.x < 256) {   // stage Wa rows 0..63 x 16 cols
                int rrow = threadIdx.x >> 2, q = threadIdx.x & 3;
                *(float4*)&ws[rrow * 16 + q * 4] =
                    *(const float4*)(wa + (size_t)rrow * 64 + kc + q * 4);
            }
            __syncthreads();
            #pragma unroll
            for (int half = 0; half < 2; ++half) {
                int kb = kc + (half << 3), co = half << 3;
                float ar[8];
                #pragma unroll
                for (int i = 0; i < 8; ++i) ar[i] = tA[n * NPAD + kb + i];
                #pragma unroll
                for (int jj = 0; jj < 8; ++jj) {
                    const float* wr = ws + (jl + jj) * 16 + co;
                    #pragma unroll
                    for (int i = 0; i < 8; ++i) acc[jj] = fmaf(wr[i], ar[i], acc[jj]);
                }
            }
            __syncthreads();
        }
        #pragma unroll
        for (int jj = 0; jj < 8; ++jj) hv[jj] = eluf(acc[jj]);
    }
    // overwrite agg tile with h (all phase-B reads of tA finished at last sync)
    #pragma unroll
    for (int jj = 0; jj < 8; ++jj) tA[n * NPAD + jl + jj] = hv[jj];
    __syncthreads();          // h tile visible

    // Phase C: GRU. r/z fuse input+hidden streams; weights via LDS broadcast.
    float a_r[8], a_z[8], a_n[8], a_h[8];
    #pragma unroll
    for (int jj = 0; jj < 8; ++jj) {
        a_r[jj] = bih[jl + jj] + bhh[jl + jj];
        a_z[jj] = bih[64 + jl + jj] + bhh[64 + jl + jj];
        a_n[jj] = bih[128 + jl + jj];
        a_h[jj] = bhh[128 + jl + jj];
    }
    for (int kcc = 0; kcc < 4; ++kcc) {
        int kc = kcc << 4;
        // stage wih(rows 0..191) + whh(rows 192..383), 16 cols each
        #pragma unroll
        for (int it = 0; it < 3; ++it) {
            int idx = threadIdx.x + (it << 9);
            int rrow = idx >> 2, q = idx & 3;   // row 0..383
            const float* src = (rrow < 192)
                ? (wih + (size_t)rrow * 64 + kc + q * 4)
                : (whh + (size_t)(rrow - 192) * 64 + kc + q * 4);
            *(float4*)&ws[rrow * 16 + q * 4] = *(const float4*)src;
        }
        __syncthreads();
        #pragma unroll
        for (int half = 0; half < 2; ++half) {
            int kb = kc + (half << 3), co = half << 3;
            float hr_[8], xr_[8];
            #pragma unroll
            for (int i = 0; i < 8; ++i) { hr_[i] = tA[n * NPAD + kb + i]; xr_[i] = tX[n * NPAD + kb + i]; }
            #pragma unroll
            for (int jj = 0; jj < 8; ++jj) {
                const float* w1 = ws + (jl + jj) * 16 + co;           // wih r
                const float* w2 = ws + (64 + jl + jj) * 16 + co;      // wih z
                const float* w3 = ws + (128 + jl + jj) * 16 + co;     // wih n
                const float* w4 = ws + (192 + jl + jj) * 16 + co;     // whh r
                const float* w5 = ws + (256 + jl + jj) * 16 + co;     // whh z
                const float* w6 = ws + (320 + jl + jj) * 16 + co;     // whh n
                #pragma unroll
                for (int i = 0; i < 8; ++i) {
                    a_r[jj] = fmaf(w1[i], hr_[i], a_r[jj]);
                    a_r[jj] = fmaf(w4[i], xr_[i], a_r[jj]);
                    a_z[jj] = fmaf(w2[i], hr_[i], a_z[jj]);
                    a_z[jj] = fmaf(w5[i], xr_[i], a_z[jj]);
                    a_n[jj] = fmaf(w3[i], hr_[i], a_n[jj]);
                    a_h[jj] = fmaf(w6[i], xr_[i], a_h[jj]);
                }
            }
        }
        __syncthreads();
    }
    #pragma unroll
    for (int jj = 0; jj < 8; ++jj) {
        float r = sigm(a_r[jj]);
        float z = sigm(a_z[jj]);
        float nn = tanhfast(a_n[jj] + r * a_h[jj]);
        float xo = tX[n * NPAD + jl + jj];
        float v = (1.f - z) * nn + z * xo;
        hv[jj] = fmaxf(v, 0.f);
    }
    #pragma unroll
    for (int jj = 0; jj < 8; ++jj) tA[n * NPAD + jl + jj] = hv[jj];
    __syncthreads();
    for (int i = threadIdx.x; i < 4096; i += 512) {
        int r = i >> 6, c = i & 63; int gr = r0 + r;
        if (gr < M) xout[(size_t)gr * 64 + c] = tA[r * NPAD + c];
    }

    // Fused align dots for the next layer: sout[n]=out.dwa, tout[n]=out.dwb
    if (sout != nullptr) {
        float wav = dwa[n], wbv = dwb[n];
        int rw = threadIdx.x >> 6;        // wave id 0..7
        #pragma unroll
        for (int q = 0; q < 8; ++q) {
            int r = rw + 8 * q; int gr = r0 + r;
            float val = tA[r * NPAD + n];
            float a = wredsum(val * wav);
            float bb = wredsum(val * wbv);
            if (n == 0 && gr < M) { sout[gr] = a; tout[gr] = bb; }
        }
    }
}

// ---------- readout: wave per graph, contiguous segment sum + relu ----------
__global__ __launch_bounds__(256) void k_seg_sum_relu(
    const float* __restrict__ x, const int* __restrict__ gst,
    float* __restrict__ outp, int G_)
{
    int g = (blockIdx.x * 256 + threadIdx.x) >> 6;
    int lane = threadIdx.x & 63;
    if (g >= G_) return;
    float S = 0.f;
    int end = gst[g + 1];
    for (int i = gst[g]; i < end; ++i) S += x[(size_t)i * 64 + lane];
    outp[(size_t)g * 64 + lane] = fmaxf(S, 0.f);
}

// ---------- mol: per-node dot of mix with align part 2 ----------
__global__ __launch_bounds__(256) void k_mol_dots(
    const float* __restrict__ xf, const float* __restrict__ cach,
    const float* __restrict__ maw, float* __restrict__ dd, int n)
{
    int wid = (blockIdx.x * 256 + threadIdx.x) >> 6;
    int lane = threadIdx.x & 63;
    if (wid >= n) return;
    float mix = 0.5f * (xf[(size_t)wid * 64 + lane] + cach[(size_t)wid * 64 + lane]);
    float v = wredsum(mix * maw[64 + lane]);
    if (lane == 0) dd[wid] = v;
}

// ---------- molecule attention: wave per graph, chunked online softmax ----------
__global__ __launch_bounds__(256) void k_mol_gather(
    const float* __restrict__ xf, const float* __restrict__ cach,
    const float* __restrict__ stateIn, const int* __restrict__ gst,
    const float* __restrict__ dd,
    const float* __restrict__ maw, const float* __restrict__ mab,
    float* __restrict__ Agg, int G_)
{
    int g = (blockIdx.x * 256 + threadIdx.x) >> 6;
    int lane = threadIdx.x & 63;
    if (g >= G_) return;
    float o = stateIn[(size_t)g * 64 + lane];
    float og = wredsum(o * maw[lane]);
    float mb = mab[0];
    int beg = gst[g], end = gst[g + 1];
    float m = -INFINITY, d = 0.f, S = 0.f;
    for (int cs = beg; cs < end; cs += 64) {
        int cnt = min(64, end - cs);
        float sc_l = -INFINITY;
        if (lane < cnt) sc_l = leaky(og + dd[cs + lane] + mb);
        float cmax = wredmax(sc_l);
        float mn = fmaxf(m, cmax);
        float c = __expf(m - mn);
        float w_l = __expf(sc_l - mn);
        d = d * c + wredsum(w_l);
        S *= c;
        int l = 0;
        for (; l + 4 <= cnt; l += 4) {
            float w0 = bcastf(w_l, l), w1 = bcastf(w_l, l + 1);
            float w2 = bcastf(w_l, l + 2), w3 = bcastf(w_l, l + 3);
            size_t r = (size_t)(cs + l) * 64 + lane;
            float m0 = 0.5f * (xf[r] + cach[r]);
            float m1 = 0.5f * (xf[r + 64] + cach[r + 64]);
            float m2 = 0.5f * (xf[r + 128] + cach[r + 128]);
            float m3 = 0.5f * (xf[r + 192] + cach[r + 192]);
            S = fmaf(w0, m0, S); S = fmaf(w1, m1, S);
            S = fmaf(w2, m2, S); S = fmaf(w3, m3, S);
        }
        for (; l < cnt; ++l) {
            float wl = bcastf(w_l, l);
            size_t r = (size_t)(cs + l) * 64 + lane;
            S = fmaf(wl, 0.5f * (xf[r] + cach[r]), S);
        }
        m = mn;
    }
    Agg[(size_t)g * 64 + lane] = S / (d + 1e-16f);
}

// ---------- final: out[g] = state[g].lin2_w + lin2_b ----------
__global__ __launch_bounds__(256) void k_lin2(
    const float* __restrict__ st, const float* __restrict__ w,
    const float* __restrict__ b, float* __restrict__ outp, int g)
{
    int gt = blockIdx.x * 256 + threadIdx.x;
    int wid = gt >> 6, lane = threadIdx.x & 63;
    if (wid >= g) return;
    float v = st[(size_t)wid * 64 + lane] * w[lane];
    #pragma unroll
    for (int off = 32; off; off >>= 1) v += __shfl_down(v, off);
    if (lane == 0) outp[wid] = v + b[0];
}

// =====================================================================
extern "C" void kernel_launch(void* const* d_in, const int* in_sizes, int n_in,
                              void* d_out, int out_size, void* d_ws, size_t ws_size,
                              hipStream_t stream) {
    const float* raw           = (const float*)d_in[0];
    const int*   ei            = (const int*)d_in[1];
    const float* ea            = (const float*)d_in[2];
    const int*   batch         = (const int*)d_in[3];
    const float* lin1_w        = (const float*)d_in[4];
    const float* lin1_b        = (const float*)d_in[5];
    const float* gate_nl_w     = (const float*)d_in[6];
    const float* gate_nl_b     = (const float*)d_in[7];
    const float* gate_align_w  = (const float*)d_in[8];
    const float* gate_align_b  = (const float*)d_in[9];
    const float* gate_attend_w = (const float*)d_in[10];
    const float* gate_attend_b = (const float*)d_in[11];
    const float* conv_align_w  = (const float*)d_in[12];
    const float* conv_align_b  = (const float*)d_in[13];
    const float* conv_attend_w = (const float*)d_in[14];
    const float* conv_attend_b = (const float*)d_in[15];
    const float* gru_wih       = (const float*)d_in[16];
    const float* gru_whh       = (const float*)d_in[17];
    const float* gru_bih       = (const float*)d_in[18];
    const float* gru_bhh       = (const float*)d_in[19];
    const float* mol_align_w   = (const float*)d_in[20];
    const float* mol_align_b   = (const float*)d_in[21];
    const float* mol_attend_w  = (const float*)d_in[22];
    const float* mol_attend_b  = (const float*)d_in[23];
    const float* mol_wih       = (const float*)d_in[24];
    const float* mol_whh       = (const float*)d_in[25];
    const float* mol_bih       = (const float*)d_in[26];
    const float* mol_bhh       = (const float*)d_in[27];
    const float* lin2_w        = (const float*)d_in[28];
    const float* lin2_b        = (const float*)d_in[29];
    float* out = (float*)d_out;

    const int N = in_sizes[3];
    const int E = in_sizes[1] / 2;
    const int G = out_size;
    const size_t N64 = (size_t)N * 64;
    const size_t G64 = (size_t)G * 64;

    // ---- workspace layout ----
    float* f = (float*)d_ws;
    float* xA    = f;
    float* xB    = xA + N64;
    float* xD    = xB + N64;
    float* Agg   = xD + N64;
    float* u     = Agg + N64;
    float* sN    = u + N64;
    float* tN    = sN + N;
    float* dd    = tN + N;
    float* outS  = dd + N;
    float* outS2 = outS + G64;
    float* aggG  = outS2 + G64;
    int* row  = (int*)(aggG + G64);
    int* csrc = row + (N + 1);
    int* ceid = csrc + E;
    int* bsum = ceid + E;
    int* gst  = bsum + 512;
    int* deg = (int*)Agg;
    int* cur = deg + N;

    const int nb_node64 = (N + 63) / 64;
    const int nb_edge   = (E + 255) / 256;
    const int nb_nodes  = (N + 255) / 256;
    const int nb_waveN  = (N + 3) / 4;
    const int nb_waveG  = (G + 3) / 4;
    const int nb_nodeG  = (G + 63) / 64;

    // ---- CSR build ----
    hipMemsetAsync(deg, 0, (size_t)N * 4, stream);
    k_hist<<<nb_edge, 256, 0, stream>>>(ei, deg, E);
    k_scan1<<<nb_nodes, 256, 0, stream>>>(deg, bsum, N);
    k_scan2<<<1, 512, 0, stream>>>(bsum, nb_nodes);
    k_scan3<<<nb_nodes, 256, 0, stream>>>(deg, bsum, row, cur, N, E);
    k_scatter<<<nb_edge, 256, 0, stream>>>(ei, cur, csrc, ceid, E);
    k_gbounds<<<nb_nodes, 256, 0, stream>>>(batch, gst, N, G);

    // ---- lin1 + gate node-part precompute ----
    k_dense64<<<nb_node64, 256, 0, stream>>>(raw, lin1_w, 64, lin1_b, xA, N, 1);
    k_dense64<<<nb_node64, 256, 0, stream>>>(raw, gate_nl_w, 80, gate_nl_b, u, N, 0);

    // ---- layer 0: GATEConv (xA -> xB); emits align dots for GAT layer 0 ----
    k_node_dot2<<<nb_waveN, 256, 0, stream>>>(xA, gate_align_w, gate_align_w, sN, tN, N, 0);
    k_gate_gather<<<nb_waveN, 256, 0, stream>>>(u, ea, row, csrc, ceid,
                                                gate_nl_w, gate_align_w, gate_align_b,
                                                sN, Agg, N);
    k_node_update<<<nb_node64, 512, 0, stream>>>(Agg, xA, gate_attend_w, gate_attend_b,
                                                 gru_wih, gru_whh, gru_bih, gru_bhh, xB, N,
                                                 conv_align_w, conv_align_w + 64, sN, tN);

    // ---- GAT layer 0 (xB -> xD); emits align dots for GAT layer 1 ----
    k_gat_gather<<<nb_waveN, 256, 0, stream>>>(row, csrc, xB, sN, tN, conv_align_b, Agg, N);
    k_node_update<<<nb_node64, 512, 0, stream>>>(Agg, xB, conv_attend_w, conv_attend_b,
                                                 gru_wih + 12288, gru_whh + 12288,
                                                 gru_bih + 192, gru_bhh + 192, xD, N,
                                                 conv_align_w + 128, conv_align_w + 192, sN, tN);

    // ---- GAT layer 1 (xD -> xA) ----
    k_gat_gather<<<nb_waveN, 256, 0, stream>>>(row, csrc, xD, sN, tN, conv_align_b + 1, Agg, N);
    k_node_update<<<nb_node64, 512, 0, stream>>>(Agg, xD, conv_attend_w + 4096, conv_attend_b + 64,
                                                 gru_wih + 24576, gru_whh + 24576,
                                                 gru_bih + 384, gru_bhh + 384, xA, N,
                                                 nullptr, nullptr, nullptr, nullptr);

    // ---- molecule readout ----
    k_seg_sum_relu<<<nb_waveG, 256, 0, stream>>>(xA, gst, outS, G);

    const float* cachedP[2] = { xD, xA };
    float* sIn = outS; float* sOut = outS2;
    for (int t = 0; t < 2; ++t) {
        k_mol_dots<<<nb_waveN, 256, 0, stream>>>(xA, cachedP[t], mol_align_w, dd, N);
        k_mol_gather<<<nb_waveG, 256, 0, stream>>>(xA, cachedP[t], sIn, gst, dd,
                                                   mol_align_w, mol_align_b, aggG, G);
        k_node_update<<<nb_nodeG, 512, 0, stream>>>(aggG, sIn, mol_attend_w, mol_attend_b,
                                                    mol_wih, mol_whh, mol_bih, mol_bhh, sOut, G,
                                                    nullptr, nullptr, nullptr, nullptr);
        float* tmp = sIn; sIn = sOut; sOut = tmp;
    }

    k_lin2<<<nb_waveG, 256, 0, stream>>>(sIn, lin2_w, lin2_b, out, G);
}

// Round 8
// 1556.753 us; speedup vs baseline: 1.9708x; 1.9708x over previous
//
#include <hip/hip_runtime.h>
#include <math.h>

#define NPAD 65

// ---------- small device helpers ----------
__device__ __forceinline__ float leaky(float x) { return x > 0.f ? x : 0.01f * x; }
__device__ __forceinline__ float eluf(float x)  { return x > 0.f ? x : (__expf(x) - 1.f); }
__device__ __forceinline__ float sigm(float x)  { return 1.f / (1.f + __expf(-x)); }
__device__ __forceinline__ float tanhfast(float x) { return 1.f - 2.f / (__expf(2.f * x) + 1.f); }

__device__ __forceinline__ float bcastf(float v, int k) {
    return __uint_as_float((unsigned)__builtin_amdgcn_readlane((int)__float_as_uint(v), k));
}
__device__ __forceinline__ int bcasti(int v, int k) {
    return __builtin_amdgcn_readlane(v, k);
}
__device__ __forceinline__ float wredsum(float v) {
    #pragma unroll
    for (int off = 32; off; off >>= 1) v += __shfl_xor(v, off);
    return v;
}
__device__ __forceinline__ float wredmax(float v) {
    #pragma unroll
    for (int off = 32; off; off >>= 1) v = fmaxf(v, __shfl_xor(v, off));
    return v;
}

// ================= CSR build =================
__global__ __launch_bounds__(256) void k_hist(const int* __restrict__ ei, int* __restrict__ deg, int E_) {
    int e = blockIdx.x * 256 + threadIdx.x;
    if (e < E_) atomicAdd(&deg[ei[E_ + e]], 1);
}

__global__ __launch_bounds__(256) void k_scan1(const int* __restrict__ deg, int* __restrict__ bsum, int N_) {
    __shared__ int s[256];
    int i = blockIdx.x * 256 + threadIdx.x;
    s[threadIdx.x] = (i < N_) ? deg[i] : 0;
    __syncthreads();
    for (int off = 128; off; off >>= 1) {
        if (threadIdx.x < off) s[threadIdx.x] += s[threadIdx.x + off];
        __syncthreads();
    }
    if (threadIdx.x == 0) bsum[blockIdx.x] = s[0];
}

// parallel exclusive scan of block sums (single block, chunked w/ carry)
__global__ __launch_bounds__(512) void k_scan2(int* __restrict__ bsum, int nb) {
    __shared__ int s[512];
    __shared__ int carry_s;
    if (threadIdx.x == 0) carry_s = 0;
    __syncthreads();
    for (int base = 0; base < nb; base += 512) {
        int t = threadIdx.x;
        int idx = base + t;
        int v = (idx < nb) ? bsum[idx] : 0;
        s[t] = v;
        __syncthreads();
        #pragma unroll
        for (int off = 1; off < 512; off <<= 1) {
            int u = (t >= off) ? s[t - off] : 0;
            __syncthreads();
            s[t] += u;
            __syncthreads();
        }
        int carry = carry_s;
        if (idx < nb) bsum[idx] = carry + s[t] - v;   // exclusive
        __syncthreads();
        if (t == 0) carry_s = carry + s[511];
        __syncthreads();
    }
}

__global__ __launch_bounds__(256) void k_scan3(const int* __restrict__ deg, const int* __restrict__ bsum,
                                               int* __restrict__ row, int* __restrict__ cur, int N_, int E_) {
    __shared__ int s[256];
    int i = blockIdx.x * 256 + threadIdx.x;
    int d = (i < N_) ? deg[i] : 0;
    s[threadIdx.x] = d;
    __syncthreads();
    for (int off = 1; off < 256; off <<= 1) {
        int v = (threadIdx.x >= off) ? s[threadIdx.x - off] : 0;
        __syncthreads();
        s[threadIdx.x] += v;
        __syncthreads();
    }
    if (i < N_) {
        int ex = bsum[blockIdx.x] + s[threadIdx.x] - d;
        row[i] = ex; cur[i] = ex;
    }
    if (i == N_ - 1) row[N_] = E_;
}

__global__ __launch_bounds__(256) void k_scatter(const int* __restrict__ ei, int* __restrict__ cur,
                                                 int* __restrict__ csrc, int* __restrict__ ceid, int E_) {
    int e = blockIdx.x * 256 + threadIdx.x;
    if (e >= E_) return;
    int dst = ei[E_ + e];
    int slot = atomicAdd(&cur[dst], 1);
    csrc[slot] = ei[e];
    ceid[slot] = e;
}

__global__ __launch_bounds__(256) void k_gbounds(const int* __restrict__ batch, int* __restrict__ gst,
                                                 int N_, int G_) {
    int i = blockIdx.x * 256 + threadIdx.x;
    if (i >= N_) return;
    int b = batch[i];
    int prev = (i == 0) ? -1 : batch[i - 1];
    for (int g = prev + 1; g <= b; ++g) gst[g] = i;
    if (i == N_ - 1) { for (int g = b + 1; g <= G_; ++g) gst[g] = N_; }
}

// ---------- dense64 (R5-proven): out = act(in @ w^T + b), direct weights ----------
__global__ __launch_bounds__(256) void k_dense64(
    const float* __restrict__ in, const float* __restrict__ w, int wstride,
    const float* __restrict__ b, float* __restrict__ outp, int M, int act)
{
    __shared__ float ti[64 * NPAD];
    __shared__ float to[64 * NPAD];
    int r0 = blockIdx.x * 64;
    for (int i = threadIdx.x; i < 4096; i += 256) {
        int r = i >> 6, c = i & 63; int gr = r0 + r;
        ti[r * NPAD + c] = (gr < M) ? in[(size_t)gr * 64 + c] : 0.f;
    }
    __syncthreads();
    int n = threadIdx.x & 63;
    int jl = __builtin_amdgcn_readfirstlane((threadIdx.x >> 6) << 4);
    float acc[16];
    #pragma unroll
    for (int jj = 0; jj < 16; ++jj) acc[jj] = b[jl + jj];
    for (int kc = 0; kc < 64; kc += 16) {
        float xr[16];
        #pragma unroll
        for (int i = 0; i < 16; ++i) xr[i] = ti[n * NPAD + kc + i];
        #pragma unroll
        for (int jj = 0; jj < 16; ++jj) {
            const float* wr = w + (jl + jj) * wstride + kc;
            #pragma unroll
            for (int i = 0; i < 16; ++i) acc[jj] = fmaf(wr[i], xr[i], acc[jj]);
        }
    }
    #pragma unroll
    for (int jj = 0; jj < 16; ++jj) {
        float v = acc[jj];
        to[n * NPAD + jl + jj] = act ? leaky(v) : v;
    }
    __syncthreads();
    for (int i = threadIdx.x; i < 4096; i += 256) {
        int r = i >> 6, c = i & 63; int gr = r0 + r;
        if (gr < M) outp[(size_t)gr * 64 + c] = to[r * NPAD + c];
    }
}

// ---------- per-node dot(s) with align vectors ----------
__global__ __launch_bounds__(256) void k_node_dot2(
    const float* __restrict__ x, const float* __restrict__ wa,
    const float* __restrict__ wb, float* __restrict__ s,
    float* __restrict__ t, int n, int two)
{
    int gt = blockIdx.x * 256 + threadIdx.x;
    int wid = gt >> 6, lane = threadIdx.x & 63;
    if (wid >= n) return;
    float xv = x[(size_t)wid * 64 + lane];
    float a = xv * wa[lane];
    float bb = two ? xv * wb[lane] : 0.f;
    #pragma unroll
    for (int off = 32; off; off >>= 1) {
        a  += __shfl_down(a, off);
        bb += __shfl_down(bb, off);
    }
    if (lane == 0) { s[wid] = a; if (two) t[wid] = bb; }
}

// ---------- GATE layer: wave per dst node, software-pipelined gather ----------
// edge l+1's u-row + ea vector are loaded before edge l's wredsum chain.
__global__ __launch_bounds__(256) void k_gate_gather(
    const float* __restrict__ u, const float* __restrict__ ea,
    const int* __restrict__ row, const int* __restrict__ csrc, const int* __restrict__ ceid,
    const float* __restrict__ wnl,
    const float* __restrict__ gaw, const float* __restrict__ gab,
    const float* __restrict__ sarr, float* __restrict__ Agg, int N_)
{
    int wid = (blockIdx.x * 256 + threadIdx.x) >> 6;
    int lane = threadIdx.x & 63;
    if (wid >= N_) return;
    float w2[16];
    #pragma unroll
    for (int k = 0; k < 16; ++k) w2[k] = wnl[lane * 80 + 64 + k];
    float g2 = gaw[64 + lane];
    float gb = gab[0];
    float sdst = sarr[wid];
    int beg = row[wid], end = row[wid + 1];
    float m = -INFINITY, d = 0.f, S = 0.f;
    for (int cs = beg; cs < end; cs += 64) {
        int cnt = min(64, end - cs);
        int src_l = 0, eid_l = 0;
        if (lane < cnt) { src_l = csrc[cs + lane]; eid_l = ceid[cs + lane]; }
        // prefetch edge 0
        int s0 = bcasti(src_l, 0), e0 = bcasti(eid_l, 0);
        float ur = u[(size_t)s0 * 64 + lane];
        float4 a0 = *(const float4*)(ea + (size_t)e0 * 16);
        float4 a1 = *(const float4*)(ea + (size_t)e0 * 16 + 4);
        float4 a2 = *(const float4*)(ea + (size_t)e0 * 16 + 8);
        float4 a3 = *(const float4*)(ea + (size_t)e0 * 16 + 12);
        for (int l = 0; l < cnt; ++l) {
            // issue next edge's loads before this edge's reduction chain
            int ln = (l + 1 < cnt) ? l + 1 : l;
            int sn = bcasti(src_l, ln), en = bcasti(eid_l, ln);
            float urn = u[(size_t)sn * 64 + lane];
            float4 b0 = *(const float4*)(ea + (size_t)en * 16);
            float4 b1 = *(const float4*)(ea + (size_t)en * 16 + 4);
            float4 b2 = *(const float4*)(ea + (size_t)en * 16 + 8);
            float4 b3 = *(const float4*)(ea + (size_t)en * 16 + 12);
            float acc = ur;
            acc = fmaf(a0.x, w2[0], acc);  acc = fmaf(a0.y, w2[1], acc);
            acc = fmaf(a0.z, w2[2], acc);  acc = fmaf(a0.w, w2[3], acc);
            acc = fmaf(a1.x, w2[4], acc);  acc = fmaf(a1.y, w2[5], acc);
            acc = fmaf(a1.z, w2[6], acc);  acc = fmaf(a1.w, w2[7], acc);
            acc = fmaf(a2.x, w2[8], acc);  acc = fmaf(a2.y, w2[9], acc);
            acc = fmaf(a2.z, w2[10], acc); acc = fmaf(a2.w, w2[11], acc);
            acc = fmaf(a3.x, w2[12], acc); acc = fmaf(a3.y, w2[13], acc);
            acc = fmaf(a3.z, w2[14], acc); acc = fmaf(a3.w, w2[15], acc);
            float xj = leaky(acc);
            float t = wredsum(xj * g2);
            float sc = leaky(sdst + t + gb);
            float mn = fmaxf(m, sc);
            float c = __expf(m - mn), w = __expf(sc - mn);
            S = S * c + w * xj;
            d = d * c + w;
            m = mn;
            ur = urn; a0 = b0; a1 = b1; a2 = b2; a3 = b3;
        }
    }
    Agg[(size_t)wid * 64 + lane] = S / (d + 1e-16f);
}

// ---------- GAT layer: wave per dst node, pipelined weighted gather ----------
__global__ __launch_bounds__(256) void k_gat_gather(
    const int* __restrict__ row, const int* __restrict__ csrc,
    const float* __restrict__ x, const float* __restrict__ sarr,
    const float* __restrict__ tarr, const float* __restrict__ cb,
    float* __restrict__ Agg, int N_)
{
    int wid = (blockIdx.x * 256 + threadIdx.x) >> 6;
    int lane = threadIdx.x & 63;
    if (wid >= N_) return;
    float sdst = sarr[wid];
    float cbv = cb[0];
    int beg = row[wid], end = row[wid + 1];
    float m = -INFINITY, d = 0.f, S = 0.f;
    for (int cs = beg; cs < end; cs += 64) {
        int cnt = min(64, end - cs);
        float sc_l = -INFINITY; int src_l = 0;
        if (lane < cnt) {
            src_l = csrc[cs + lane];
            sc_l = leaky(sdst + tarr[src_l] + cbv);
        }
        float cmax = wredmax(sc_l);
        float mn = fmaxf(m, cmax);
        float c = __expf(m - mn);
        float w_l = __expf(sc_l - mn);   // 0 for lanes >= cnt
        d = d * c + wredsum(w_l);
        S *= c;
        // rows in groups of 4, one group prefetched ahead; lanes >= cnt have
        // w_l = 0 so rounding cnt up to x4 adds harmless zero-weight rows.
        int cnt4 = (cnt + 3) & ~3;
        int s0 = bcasti(src_l, 0), s1 = bcasti(src_l, 1);
        int s2 = bcasti(src_l, 2), s3 = bcasti(src_l, 3);
        float r0 = x[(size_t)s0 * 64 + lane];
        float r1 = x[(size_t)s1 * 64 + lane];
        float r2 = x[(size_t)s2 * 64 + lane];
        float r3 = x[(size_t)s3 * 64 + lane];
        for (int l = 0; l < cnt4; l += 4) {
            int ln = (l + 4 < cnt4) ? l + 4 : 0;
            int t0 = bcasti(src_l, ln),     t1 = bcasti(src_l, ln + 1);
            int t2 = bcasti(src_l, ln + 2), t3 = bcasti(src_l, ln + 3);
            float p0 = x[(size_t)t0 * 64 + lane];
            float p1 = x[(size_t)t1 * 64 + lane];
            float p2 = x[(size_t)t2 * 64 + lane];
            float p3 = x[(size_t)t3 * 64 + lane];
            float w0 = bcastf(w_l, l),     w1 = bcastf(w_l, l + 1);
            float w2 = bcastf(w_l, l + 2), w3 = bcastf(w_l, l + 3);
            S = fmaf(w0, r0, S); S = fmaf(w1, r1, S);
            S = fmaf(w2, r2, S); S = fmaf(w3, r3, S);
            r0 = p0; r1 = p1; r2 = p2; r3 = p3;
        }
        m = mn;
    }
    Agg[(size_t)wid * 64 + lane] = S / (d + 1e-16f);
}

// ---------- fused node update (R4-proven body + fused align-dot epilogue) ----------
__global__ __launch_bounds__(512) void k_node_update(
    const float* __restrict__ agg, const float* __restrict__ xold,
    const float* __restrict__ wa, const float* __restrict__ ba,
    const float* __restrict__ wih, const float* __restrict__ whh,
    const float* __restrict__ bih, const float* __restrict__ bhh,
    float* __restrict__ xout, int M,
    const float* __restrict__ dwa, const float* __restrict__ dwb,
    float* __restrict__ sout, float* __restrict__ tout)
{
    __shared__ float tA[64 * NPAD];   // agg tile, then h tile, then out tile
    __shared__ float tX[64 * NPAD];   // xold tile
    int r0 = blockIdx.x * 64;
    for (int i = threadIdx.x; i < 4096; i += 512) {
        int r = i >> 6, c = i & 63; int gr = r0 + r;
        float av = 0.f, xv = 0.f;
        if (gr < M) { av = agg[(size_t)gr * 64 + c]; xv = xold[(size_t)gr * 64 + c]; }
        tA[r * NPAD + c] = av; tX[r * NPAD + c] = xv;
    }
    __syncthreads();
    int n = threadIdx.x & 63;
    int jl = __builtin_amdgcn_readfirstlane((threadIdx.x >> 6) << 3);  // 0..56

    // Phase B: h[jl..jl+8) = elu(Agg @ Wa^T + ba)
    float hv[8];
    {
        float acc[8];
        #pragma unroll
        for (int jj = 0; jj < 8; ++jj) acc[jj] = ba[jl + jj];
        for (int kc = 0; kc < 64; kc += 16) {
            float ar[16];
            #pragma unroll
            for (int i = 0; i < 16; ++i) ar[i] = tA[n * NPAD + kc + i];
            #pragma unroll
            for (int jj = 0; jj < 8; ++jj) {
                const float* wr = wa + (jl + jj) * 64 + kc;
                #pragma unroll
                for (int i = 0; i < 16; ++i) acc[jj] = fmaf(wr[i], ar[i], acc[jj]);
            }
        }
        #pragma unroll
        for (int jj = 0; jj < 8; ++jj) hv[jj] = eluf(acc[jj]);
    }
    __syncthreads();          // all phase-B reads of tA done
    #pragma unroll
    for (int jj = 0; jj < 8; ++jj) tA[n * NPAD + jl + jj] = hv[jj];
    __syncthreads();          // h tile visible

    // Phase C: GRU. r/z accumulate both input+hidden streams in one register.
    float a_r[8], a_z[8], a_n[8], a_h[8];
    #pragma unroll
    for (int jj = 0; jj < 8; ++jj) {
        a_r[jj] = bih[jl + jj] + bhh[jl + jj];
        a_z[jj] = bih[64 + jl + jj] + bhh[64 + jl + jj];
        a_n[jj] = bih[128 + jl + jj];
        a_h[jj] = bhh[128 + jl + jj];
    }
    for (int kc = 0; kc < 64; kc += 8) {
        float hr_[8], xr_[8];
        #pragma unroll
        for (int i = 0; i < 8; ++i) { hr_[i] = tA[n * NPAD + kc + i]; xr_[i] = tX[n * NPAD + kc + i]; }
        #pragma unroll
        for (int jj = 0; jj < 8; ++jj) {
            const float* w1 = wih + (jl + jj) * 64 + kc;          // r, input
            const float* w4 = whh + (jl + jj) * 64 + kc;          // r, hidden
            const float* w2 = wih + (64 + jl + jj) * 64 + kc;     // z, input
            const float* w5 = whh + (64 + jl + jj) * 64 + kc;     // z, hidden
            const float* w3 = wih + (128 + jl + jj) * 64 + kc;    // n, input
            const float* w6 = whh + (128 + jl + jj) * 64 + kc;    // n, hidden
            #pragma unroll
            for (int i = 0; i < 8; ++i) {
                a_r[jj] = fmaf(w1[i], hr_[i], a_r[jj]);
                a_r[jj] = fmaf(w4[i], xr_[i], a_r[jj]);
                a_z[jj] = fmaf(w2[i], hr_[i], a_z[jj]);
                a_z[jj] = fmaf(w5[i], xr_[i], a_z[jj]);
                a_n[jj] = fmaf(w3[i], hr_[i], a_n[jj]);
                a_h[jj] = fmaf(w6[i], xr_[i], a_h[jj]);
            }
        }
    }
    #pragma unroll
    for (int jj = 0; jj < 8; ++jj) {
        float r = sigm(a_r[jj]);
        float z = sigm(a_z[jj]);
        float nn = tanhfast(a_n[jj] + r * a_h[jj]);
        float xo = tX[n * NPAD + jl + jj];
        float v = (1.f - z) * nn + z * xo;
        hv[jj] = fmaxf(v, 0.f);
    }
    __syncthreads();          // all phase-C reads of tA done
    #pragma unroll
    for (int jj = 0; jj < 8; ++jj) tA[n * NPAD + jl + jj] = hv[jj];
    __syncthreads();
    for (int i = threadIdx.x; i < 4096; i += 512) {
        int r = i >> 6, c = i & 63; int gr = r0 + r;
        if (gr < M) xout[(size_t)gr * 64 + c] = tA[r * NPAD + c];
    }

    // Fused align dots for the next layer: sout[n]=out.dwa, tout[n]=out.dwb
    if (sout != nullptr) {
        float wav = dwa[n], wbv = dwb[n];
        int rw = threadIdx.x >> 6;        // wave id 0..7
        #pragma unroll
        for (int q = 0; q < 8; ++q) {
            int r = rw + 8 * q; int gr = r0 + r;
            float val = tA[r * NPAD + n];
            float a = wredsum(val * wav);
            float bb = wredsum(val * wbv);
            if (n == 0 && gr < M) { sout[gr] = a; tout[gr] = bb; }
        }
    }
}

// ---------- readout: wave per graph, contiguous segment sum + relu ----------
__global__ __launch_bounds__(256) void k_seg_sum_relu(
    const float* __restrict__ x, const int* __restrict__ gst,
    float* __restrict__ outp, int G_)
{
    int g = (blockIdx.x * 256 + threadIdx.x) >> 6;
    int lane = threadIdx.x & 63;
    if (g >= G_) return;
    float S = 0.f;
    int end = gst[g + 1];
    for (int i = gst[g]; i < end; ++i) S += x[(size_t)i * 64 + lane];
    outp[(size_t)g * 64 + lane] = fmaxf(S, 0.f);
}

// ---------- mol: per-node dot of mix with align part 2 ----------
__global__ __launch_bounds__(256) void k_mol_dots(
    const float* __restrict__ xf, const float* __restrict__ cach,
    const float* __restrict__ maw, float* __restrict__ dd, int n)
{
    int wid = (blockIdx.x * 256 + threadIdx.x) >> 6;
    int lane = threadIdx.x & 63;
    if (wid >= n) return;
    float mix = 0.5f * (xf[(size_t)wid * 64 + lane] + cach[(size_t)wid * 64 + lane]);
    float v = wredsum(mix * maw[64 + lane]);
    if (lane == 0) dd[wid] = v;
}

// ---------- molecule attention: wave per graph, pipelined gather ----------
__global__ __launch_bounds__(256) void k_mol_gather(
    const float* __restrict__ xf, const float* __restrict__ cach,
    const float* __restrict__ stateIn, const int* __restrict__ gst,
    const float* __restrict__ dd,
    const float* __restrict__ maw, const float* __restrict__ mab,
    float* __restrict__ Agg, int G_)
{
    int g = (blockIdx.x * 256 + threadIdx.x) >> 6;
    int lane = threadIdx.x & 63;
    if (g >= G_) return;
    float o = stateIn[(size_t)g * 64 + lane];
    float og = wredsum(o * maw[lane]);
    float mb = mab[0];
    int beg = gst[g], end = gst[g + 1];
    float m = -INFINITY, d = 0.f, S = 0.f;
    for (int cs = beg; cs < end; cs += 64) {
        int cnt = min(64, end - cs);
        float sc_l = -INFINITY;
        if (lane < cnt) sc_l = leaky(og + dd[cs + lane] + mb);
        float cmax = wredmax(sc_l);
        float mn = fmaxf(m, cmax);
        float c = __expf(m - mn);
        float w_l = __expf(sc_l - mn);   // 0 for lanes >= cnt
        d = d * c + wredsum(w_l);
        S *= c;
        int cnt4 = (cnt + 3) & ~3;
        size_t rb = (size_t)cs * 64 + lane;
        float x0 = xf[rb],      c0 = cach[rb];
        float x1 = xf[rb + 64], c1 = cach[rb + 64];
        float x2 = xf[rb + 128], c2 = cach[rb + 128];
        float x3 = xf[rb + 192], c3 = cach[rb + 192];
        for (int l = 0; l < cnt4; l += 4) {
            int ln = (l + 4 < cnt4) ? l + 4 : 0;
            size_t rn = (size_t)(cs + ln) * 64 + lane;
            float y0 = xf[rn],       d0 = cach[rn];
            float y1 = xf[rn + 64],  d1 = cach[rn + 64];
            float y2 = xf[rn + 128], d2 = cach[rn + 128];
            float y3 = xf[rn + 192], d3 = cach[rn + 192];
            float w0 = bcastf(w_l, l),     w1 = bcastf(w_l, l + 1);
            float w2 = bcastf(w_l, l + 2), w3 = bcastf(w_l, l + 3);
            S = fmaf(w0, 0.5f * (x0 + c0), S);
            S = fmaf(w1, 0.5f * (x1 + c1), S);
            S = fmaf(w2, 0.5f * (x2 + c2), S);
            S = fmaf(w3, 0.5f * (x3 + c3), S);
            x0 = y0; c0 = d0; x1 = y1; c1 = d1;
            x2 = y2; c2 = d2; x3 = y3; c3 = d3;
        }
        m = mn;
    }
    Agg[(size_t)g * 64 + lane] = S / (d + 1e-16f);
}

// ---------- final: out[g] = state[g].lin2_w + lin2_b ----------
__global__ __launch_bounds__(256) void k_lin2(
    const float* __restrict__ st, const float* __restrict__ w,
    const float* __restrict__ b, float* __restrict__ outp, int g)
{
    int gt = blockIdx.x * 256 + threadIdx.x;
    int wid = gt >> 6, lane = threadIdx.x & 63;
    if (wid >= g) return;
    float v = st[(size_t)wid * 64 + lane] * w[lane];
    #pragma unroll
    for (int off = 32; off; off >>= 1) v += __shfl_down(v, off);
    if (lane == 0) outp[wid] = v + b[0];
}

// =====================================================================
extern "C" void kernel_launch(void* const* d_in, const int* in_sizes, int n_in,
                              void* d_out, int out_size, void* d_ws, size_t ws_size,
                              hipStream_t stream) {
    const float* raw           = (const float*)d_in[0];
    const int*   ei            = (const int*)d_in[1];
    const float* ea            = (const float*)d_in[2];
    const int*   batch         = (const int*)d_in[3];
    const float* lin1_w        = (const float*)d_in[4];
    const float* lin1_b        = (const float*)d_in[5];
    const float* gate_nl_w     = (const float*)d_in[6];
    const float* gate_nl_b     = (const float*)d_in[7];
    const float* gate_align_w  = (const float*)d_in[8];
    const float* gate_align_b  = (const float*)d_in[9];
    const float* gate_attend_w = (const float*)d_in[10];
    const float* gate_attend_b = (const float*)d_in[11];
    const float* conv_align_w  = (const float*)d_in[12];
    const float* conv_align_b  = (const float*)d_in[13];
    const float* conv_attend_w = (const float*)d_in[14];
    const float* conv_attend_b = (const float*)d_in[15];
    const float* gru_wih       = (const float*)d_in[16];
    const float* gru_whh       = (const float*)d_in[17];
    const float* gru_bih       = (const float*)d_in[18];
    const float* gru_bhh       = (const float*)d_in[19];
    const float* mol_align_w   = (const float*)d_in[20];
    const float* mol_align_b   = (const float*)d_in[21];
    const float* mol_attend_w  = (const float*)d_in[22];
    const float* mol_attend_b  = (const float*)d_in[23];
    const float* mol_wih       = (const float*)d_in[24];
    const float* mol_whh       = (const float*)d_in[25];
    const float* mol_bih       = (const float*)d_in[26];
    const float* mol_bhh       = (const float*)d_in[27];
    const float* lin2_w        = (const float*)d_in[28];
    const float* lin2_b        = (const float*)d_in[29];
    float* out = (float*)d_out;

    const int N = in_sizes[3];
    const int E = in_sizes[1] / 2;
    const int G = out_size;
    const size_t N64 = (size_t)N * 64;
    const size_t G64 = (size_t)G * 64;

    // ---- workspace layout ----
    float* f = (float*)d_ws;
    float* xA    = f;
    float* xB    = xA + N64;
    float* xD    = xB + N64;
    float* Agg   = xD + N64;
    float* u     = Agg + N64;
    float* sN    = u + N64;
    float* tN    = sN + N;
    float* dd    = tN + N;
    float* outS  = dd + N;
    float* outS2 = outS + G64;
    float* aggG  = outS2 + G64;
    int* row  = (int*)(aggG + G64);
    int* csrc = row + (N + 1);
    int* ceid = csrc + E;
    int* bsum = ceid + E;
    int* gst  = bsum + 512;
    int* deg = (int*)Agg;
    int* cur = deg + N;

    const int nb_node64 = (N + 63) / 64;
    const int nb_edge   = (E + 255) / 256;
    const int nb_nodes  = (N + 255) / 256;
    const int nb_waveN  = (N + 3) / 4;
    const int nb_waveG  = (G + 3) / 4;
    const int nb_nodeG  = (G + 63) / 64;

    // ---- CSR build ----
    hipMemsetAsync(deg, 0, (size_t)N * 4, stream);
    k_hist<<<nb_edge, 256, 0, stream>>>(ei, deg, E);
    k_scan1<<<nb_nodes, 256, 0, stream>>>(deg, bsum, N);
    k_scan2<<<1, 512, 0, stream>>>(bsum, nb_nodes);
    k_scan3<<<nb_nodes, 256, 0, stream>>>(deg, bsum, row, cur, N, E);
    k_scatter<<<nb_edge, 256, 0, stream>>>(ei, cur, csrc, ceid, E);
    k_gbounds<<<nb_nodes, 256, 0, stream>>>(batch, gst, N, G);

    // ---- lin1 + gate node-part precompute ----
    k_dense64<<<nb_node64, 256, 0, stream>>>(raw, lin1_w, 64, lin1_b, xA, N, 1);
    k_dense64<<<nb_node64, 256, 0, stream>>>(raw, gate_nl_w, 80, gate_nl_b, u, N, 0);

    // ---- layer 0: GATEConv (xA -> xB); emits align dots for GAT layer 0 ----
    k_node_dot2<<<nb_waveN, 256, 0, stream>>>(xA, gate_align_w, gate_align_w, sN, tN, N, 0);
    k_gate_gather<<<nb_waveN, 256, 0, stream>>>(u, ea, row, csrc, ceid,
                                                gate_nl_w, gate_align_w, gate_align_b,
                                                sN, Agg, N);
    k_node_update<<<nb_node64, 512, 0, stream>>>(Agg, xA, gate_attend_w, gate_attend_b,
                                                 gru_wih, gru_whh, gru_bih, gru_bhh, xB, N,
                                                 conv_align_w, conv_align_w + 64, sN, tN);

    // ---- GAT layer 0 (xB -> xD); emits align dots for GAT layer 1 ----
    k_gat_gather<<<nb_waveN, 256, 0, stream>>>(row, csrc, xB, sN, tN, conv_align_b, Agg, N);
    k_node_update<<<nb_node64, 512, 0, stream>>>(Agg, xB, conv_attend_w, conv_attend_b,
                                                 gru_wih + 12288, gru_whh + 12288,
                                                 gru_bih + 192, gru_bhh + 192, xD, N,
                                                 conv_align_w + 128, conv_align_w + 192, sN, tN);

    // ---- GAT layer 1 (xD -> xA) ----
    k_gat_gather<<<nb_waveN, 256, 0, stream>>>(row, csrc, xD, sN, tN, conv_align_b + 1, Agg, N);
    k_node_update<<<nb_node64, 512, 0, stream>>>(Agg, xD, conv_attend_w + 4096, conv_attend_b + 64,
                                                 gru_wih + 24576, gru_whh + 24576,
                                                 gru_bih + 384, gru_bhh + 384, xA, N,
                                                 nullptr, nullptr, nullptr, nullptr);

    // ---- molecule readout ----
    k_seg_sum_relu<<<nb_waveG, 256, 0, stream>>>(xA, gst, outS, G);

    const float* cachedP[2] = { xD, xA };
    float* sIn = outS; float* sOut = outS2;
    for (int t = 0; t < 2; ++t) {
        k_mol_dots<<<nb_waveN, 256, 0, stream>>>(xA, cachedP[t], mol_align_w, dd, N);
        k_mol_gather<<<nb_waveG, 256, 0, stream>>>(xA, cachedP[t], sIn, gst, dd,
                                                   mol_align_w, mol_align_b, aggG, G);
        k_node_update<<<nb_nodeG, 512, 0, stream>>>(aggG, sIn, mol_attend_w, mol_attend_b,
                                                    mol_wih, mol_whh, mol_bih, mol_bhh, sOut, G,
                                                    nullptr, nullptr, nullptr, nullptr);
        float* tmp = sIn; sIn = sOut; sOut = tmp;
    }

    k_lin2<<<nb_waveG, 256, 0, stream>>>(sIn, lin2_w, lin2_b, out, G);
}